// Round 5
// baseline (354.774 us; speedup 1.0000x reference)
//
#include <hip/hip_runtime.h>
#include <math.h>

typedef unsigned long long u64;
typedef unsigned int u32;

#define M_ANCH 360000
#define NCLS 80
#define KTOP 1000
#define CAP 8192
#define NBINS 65536
#define RREP 8
#define CONF_THRESH 0.05f
#define NMS_THRESH 0.6f
#define CTR_CLAMP 32.0f
#define SCALE_CLAMP 4.1351665567423560f  /* log(1000/16) */

/* ---- workspace layout (bytes) ---- */
#define HIST_OFF   0u
#define HIST_BYTES (RREP * NBINS * 4u)            /* 2,097,152 */
#define MERGED_OFF (HIST_OFF + HIST_BYTES)        /* 65536*4 = 262,144 */
#define BLKSUM_OFF (MERGED_OFF + NBINS * 4u)      /* 64*4 = 256 */
#define CNT_OFF    (BLKSUM_OFF + 256u)
#define B_OFF      (CNT_OFF + 4u)
#define VW_OFF     (B_OFF + 4u)                   /* 16 u64 = 128 B (8-aligned) */
#define ZERO_END   (VW_OFF + 128u)
#define CAND_OFF   ZERO_END                       /* 8192 * 8 */
#define SC_OFF     (CAND_OFF + CAP * 8u)          /* M floats */
#define CLS_OFF    (SC_OFF + M_ANCH * 4u)         /* M ints */
#define SSC_OFF    (CLS_OFF + M_ANCH * 4u)        /* 1000 floats */
#define SCLS_OFF   (SSC_OFF + KTOP * 4u)          /* 1000 ints */
#define SUP_OFF    (SCLS_OFF + KTOP * 4u)         /* 16000 u64 */

__device__ __forceinline__ u32 fkey(float f) {
    u32 u = __float_as_uint(f);
    return (u & 0x80000000u) ? ~u : (u | 0x80000000u);
}

/* K1: block owns 64 anchors = 1280 contiguous float4s = 20 KB.
   Phase 1: 5 block-stride float4 loads (perfectly coalesced), per-float4 max
   -> LDS with stride-21 padding. Phase 2: 64 threads reduce 20 slots each. */
__global__ __launch_bounds__(256) void k_score(const float* __restrict__ cls_pred,
                                               float* __restrict__ sc_all,
                                               int* __restrict__ cls_all,
                                               u32* __restrict__ hist) {
    __shared__ float lm[64 * 21];
    __shared__ int   lc[64 * 21];
    int t = threadIdx.x;
    const float4* p = (const float4*)cls_pred + (size_t)blockIdx.x * 1280;
    float4 v0 = p[t];
    float4 v1 = p[t + 256];
    float4 v2 = p[t + 512];
    float4 v3 = p[t + 768];
    float4 v4 = p[t + 1024];
#pragma unroll
    for (int k = 0; k < 5; k++) {
        float4 v = (k == 0) ? v0 : (k == 1) ? v1 : (k == 2) ? v2 : (k == 3) ? v3 : v4;
        int f = t + 256 * k;      /* [0, 1280) */
        int a = f / 20;           /* local anchor [0, 64) */
        int s = f % 20;           /* slot [0, 20) */
        float mv = v.x; int mc = 0;
        if (v.y > mv) { mv = v.y; mc = 1; }
        if (v.z > mv) { mv = v.z; mc = 2; }
        if (v.w > mv) { mv = v.w; mc = 3; }
        lm[a * 21 + s] = mv;
        lc[a * 21 + s] = s * 4 + mc;
    }
    __syncthreads();
    if (t < 64) {
        float mv = -1e30f; int mc = 0;
#pragma unroll
        for (int s = 0; s < 20; s++) {
            float m = lm[t * 21 + s];
            int c = lc[t * 21 + s];
            if (m > mv) { mv = m; mc = c; }
        }
        int a = blockIdx.x * 64 + t;
        float sc = 1.0f / (1.0f + expf(-mv));
        sc_all[a] = sc;
        cls_all[a] = mc;
        float msk = (sc >= CONF_THRESH) ? sc : -1.0f;
        u32 u = fkey(msk);
        atomicAdd(&hist[((blockIdx.x & (RREP - 1)) << 16) + (u >> 16)], 1u);
    }
}

/* K2a: merge RREP histogram replicas (coalesced), emit per-1024-bin block sums */
__global__ __launch_bounds__(1024) void k_hsum(const u32* __restrict__ hist,
                                               u32* __restrict__ merged,
                                               u32* __restrict__ blksum) {
    __shared__ u32 red[1024];
    int t = threadIdx.x;
    int b = blockIdx.x * 1024 + t;
    u32 s = 0;
#pragma unroll
    for (int r = 0; r < RREP; r++) s += hist[r * NBINS + b];
    merged[b] = s;
    red[t] = s;
    __syncthreads();
    for (int off = 512; off > 0; off >>= 1) {
        if (t < off) red[t] += red[t + off];
        __syncthreads();
    }
    if (t == 0) blksum[blockIdx.x] = red[0];
}

/* K2b: find boundary bin B = max b with count(bins >= b) >= KTOP */
__global__ __launch_bounds__(1024) void k_boundary(const u32* __restrict__ merged,
                                                   const u32* __restrict__ blksum,
                                                   u32* __restrict__ outB) {
    __shared__ u32 bs[64];
    __shared__ u32 sj, sA;
    __shared__ u32 csum[1024];
    int t = threadIdx.x;
    if (t < 64) bs[t] = blksum[t];
    __syncthreads();
    if (t == 0) {
        u32 cum = 0; u32 j = 0; u32 Aj = 0;
        for (int b = 63; b >= 0; b--) {
            if (cum + bs[b] >= KTOP) { j = (u32)b; Aj = cum; break; }
            cum += bs[b];
        }
        sj = j; sA = Aj;
    }
    __syncthreads();
    u32 j = sj, Aj = sA;
    u32 h = merged[j * 1024 + t];
    csum[t] = h;
    __syncthreads();
    u32 v = h;
    for (int off = 1; off < 1024; off <<= 1) {
        u32 add = (t + off < 1024) ? csum[t + off] : 0u;
        __syncthreads();
        v += add;
        csum[t] = v;
        __syncthreads();
    }
    u32 above = (t == 1023) ? 0u : csum[t + 1];
    if (Aj + above < KTOP && Aj + above + h >= KTOP) outB[0] = j * 1024 + t;
}

/* K3: compact candidates (key bin >= B). Candidate SET is deterministic;
   order is not, but K4 sorts. CAP=8192 gives wide overflow margin. */
__global__ __launch_bounds__(256) void k_compact(const float* __restrict__ sc_all,
                                                 const u32* __restrict__ pB,
                                                 u32* __restrict__ counter,
                                                 u64* __restrict__ cand) {
    int i = blockIdx.x * 256 + threadIdx.x;
    if (i >= M_ANCH) return;
    u32 B = *pB;
    float s = sc_all[i];
    float m = (s >= CONF_THRESH) ? s : -1.0f;
    u32 u = fkey(m);
    if ((u >> 16) >= B) {
        u32 pos = atomicAdd(counter, 1u);
        if (pos < CAP) cand[pos] = ((u64)u << 32) | (u64)(0xFFFFFFFFu - (u32)i);
    }
}

/* K4: adaptive bitonic sort (P = next pow2 >= n, min 1024), top 1000, decode */
__global__ __launch_bounds__(1024) void k_select(const u64* __restrict__ cand,
                                                 const u32* __restrict__ counter,
                                                 const float* __restrict__ sc_all,
                                                 const int* __restrict__ cls_all,
                                                 const float* __restrict__ reg_pred,
                                                 const float* __restrict__ anchors,
                                                 float* __restrict__ out,
                                                 float* __restrict__ sel_sc,
                                                 int* __restrict__ sel_cls,
                                                 u64* __restrict__ valid_words) {
    __shared__ u64 keys[CAP];
    int t = threadIdx.x;
    u32 n = *counter;
    if (n > CAP) n = CAP;
    u32 P = 1024;
    while (P < n) P <<= 1;            /* P in {1024,...,8192} */
    for (u32 i = t; i < P; i += 1024) keys[i] = (i < n) ? cand[i] : 0ull;
    for (u32 k = 2; k <= P; k <<= 1) {
        for (u32 j = k >> 1; j > 0; j >>= 1) {
            __syncthreads();
            for (u32 i = t; i < P; i += 1024) {
                u32 ixj = i ^ j;
                if (ixj > i) {
                    u64 a = keys[i], b = keys[ixj];
                    bool desc = ((i & k) == 0);
                    if (desc ? (a < b) : (a > b)) { keys[i] = b; keys[ixj] = a; }
                }
            }
        }
    }
    __syncthreads();
    if (t < KTOP) {
        u64 key = keys[t];
        u32 idx = 0xFFFFFFFFu - (u32)(key & 0xFFFFFFFFull);
        if (idx >= M_ANCH) idx = 0;
        float s = sc_all[idx];
        int cl = cls_all[idx];
        float4 a = ((const float4*)anchors)[idx];
        float4 r = ((const float4*)reg_pred)[idx];
        float ox = fminf(fmaxf(r.x * a.z, -CTR_CLAMP), CTR_CLAMP);
        float oy = fminf(fmaxf(r.y * a.w, -CTR_CLAMP), CTR_CLAMP);
        float cx = a.x + ox, cy = a.y + oy;
        float ww = a.z * expf(fminf(r.z, SCALE_CLAMP));
        float hh = a.w * expf(fminf(r.w, SCALE_CLAMP));
        float4 box;
        box.x = cx - 0.5f * ww;
        box.y = cy - 0.5f * hh;
        box.z = cx + 0.5f * ww;
        box.w = cy + 0.5f * hh;
        ((float4*)out)[t] = box;                 /* boxes: out[0..3999] */
        out[5 * KTOP + t] = (float)cl;           /* classes: out[5000..5999] */
        sel_sc[t] = s;
        sel_cls[t] = cl;
        if (s >= CONF_THRESH) atomicOr(&valid_words[t >> 6], 1ull << (t & 63));
    }
}

/* K5: suppression matrix — one wave computes one 64-wide word via ballot */
__global__ __launch_bounds__(256) void k_supmat(const float* __restrict__ out,
                                                const int* __restrict__ sel_cls,
                                                u64* __restrict__ sup) {
    int wid = threadIdx.x >> 6;
    int lane = threadIdx.x & 63;
    int g = blockIdx.x * 4 + wid;          /* g in [0, 16000) */
    int i = g >> 4;
    int w = g & 15;
    int j = w * 64 + lane;
    int jc = (j < KTOP) ? j : (KTOP - 1);
    float4 bi = ((const float4*)out)[i];
    float4 bj = ((const float4*)out)[jc];
    int ci = sel_cls[i], cj = sel_cls[jc];
    float ai = (bi.z - bi.x) * (bi.w - bi.y);
    float aj = (bj.z - bj.x) * (bj.w - bj.y);
    float xx1 = fmaxf(bi.x, bj.x), yy1 = fmaxf(bi.y, bj.y);
    float xx2 = fminf(bi.z, bj.z), yy2 = fminf(bi.w, bj.w);
    float iw = fmaxf(1e-28f, xx2 - xx1), ih = fmaxf(1e-28f, yy2 - yy1);
    float inter = iw * ih;
    float iou = inter / (ai + aj - inter + 1e-14f);
    bool pred = (j < i) && (ci == cj) && (iou > NMS_THRESH);
    u64 bal = __ballot((int)pred);
    if (lane == 0) sup[g] = bal;
}

/* K6: sequential greedy NMS scan, single wave. Lane l (l<16) owns keep word l.
   Depth-8 software pipeline of NAMED u64 registers (unroll 8, 1000=8*125) so
   the row loads are register-resident and issued 8 rows ahead of use. Valid
   bits come from a per-lane register: only lane i>>6 consumes bit i, and that
   lane's own word is the correct one. */
__global__ __launch_bounds__(64) void k_nms(const u64* __restrict__ sup,
                                            const u64* __restrict__ valid_words,
                                            const float* __restrict__ sel_sc,
                                            float* __restrict__ out) {
    __shared__ u64 kw[16];
    int lane = threadIdx.x;
    int wsel = lane & 15;
    u64 vloc = valid_words[wsel];
    u64 keepw = 0ull;

    u64 p0 = sup[0 * 16 + wsel];
    u64 p1 = sup[1 * 16 + wsel];
    u64 p2 = sup[2 * 16 + wsel];
    u64 p3 = sup[3 * 16 + wsel];
    u64 p4 = sup[4 * 16 + wsel];
    u64 p5 = sup[5 * 16 + wsel];
    u64 p6 = sup[6 * 16 + wsel];
    u64 p7 = sup[7 * 16 + wsel];

#pragma unroll 8
    for (int i = 0; i < KTOP; i++) {
        u64 x = (lane < 16) ? (p0 & keepw) : 0ull;
        int supd = __any(x != 0ull);
        int vi = (int)((vloc >> (i & 63)) & 1ull);
        bool upd = (!supd) && vi && (lane == (i >> 6));
        if (upd) keepw |= (1ull << (i & 63));
        p0 = p1; p1 = p2; p2 = p3; p3 = p4; p4 = p5; p5 = p6; p6 = p7;
        int nr = i + 8;
        int nra = (nr < KTOP) ? nr : (KTOP - 1);
        u64 nv = sup[nra * 16 + wsel];
        p7 = (nr < KTOP) ? nv : 0ull;
    }
    if (lane < 16) kw[lane] = keepw;
    __syncthreads();
    for (int t = lane; t < KTOP; t += 64) {
        int kb = (int)((kw[t >> 6] >> (t & 63)) & 1ull);
        float s = sel_sc[t];
        out[4 * KTOP + t] = kb ? s : 0.0f;   /* scores*keep: out[4000..4999] */
        out[6 * KTOP + t] = (float)kb;       /* keep:        out[6000..6999] */
    }
}

extern "C" void kernel_launch(void* const* d_in, const int* in_sizes, int n_in,
                              void* d_out, int out_size, void* d_ws, size_t ws_size,
                              hipStream_t stream) {
    const float* cls_pred = (const float*)d_in[0];
    const float* reg_pred = (const float*)d_in[1];
    const float* anchors  = (const float*)d_in[2];
    float* out = (float*)d_out;
    char* ws = (char*)d_ws;

    u32* hist     = (u32*)(ws + HIST_OFF);
    u32* merged   = (u32*)(ws + MERGED_OFF);
    u32* blksum   = (u32*)(ws + BLKSUM_OFF);
    u32* counter  = (u32*)(ws + CNT_OFF);
    u32* pB       = (u32*)(ws + B_OFF);
    u64* vwords   = (u64*)(ws + VW_OFF);
    u64* cand     = (u64*)(ws + CAND_OFF);
    float* sc_all = (float*)(ws + SC_OFF);
    int* cls_all  = (int*)(ws + CLS_OFF);
    float* sel_sc = (float*)(ws + SSC_OFF);
    int* sel_cls  = (int*)(ws + SCLS_OFF);
    u64* sup      = (u64*)(ws + SUP_OFF);

    hipMemsetAsync(d_ws, 0, ZERO_END, stream);

    int nbs = M_ANCH / 64;            /* 5625 blocks, 64 anchors each */
    int nbc = (M_ANCH + 255) / 256;
    k_score<<<nbs, 256, 0, stream>>>(cls_pred, sc_all, cls_all, hist);
    k_hsum<<<NBINS / 1024, 1024, 0, stream>>>(hist, merged, blksum);
    k_boundary<<<1, 1024, 0, stream>>>(merged, blksum, pB);
    k_compact<<<nbc, 256, 0, stream>>>(sc_all, pB, counter, cand);
    k_select<<<1, 1024, 0, stream>>>(cand, counter, sc_all, cls_all, reg_pred,
                                     anchors, out, sel_sc, sel_cls, vwords);
    k_supmat<<<(KTOP * 16) / 4, 256, 0, stream>>>(out, sel_cls, sup);
    k_nms<<<1, 64, 0, stream>>>(sup, vwords, sel_sc, out);
}

// Round 6
// 320.285 us; speedup vs baseline: 1.1077x; 1.1077x over previous
//
#include <hip/hip_runtime.h>
#include <math.h>

typedef unsigned long long u64;
typedef unsigned int u32;

#define M_ANCH 360000
#define NCLS 80
#define KTOP 1000
#define CAP 8192
#define NBINS 65536
#define RREP 8
#define CONF_THRESH 0.05f
#define NMS_THRESH 0.6f
#define CTR_CLAMP 32.0f
#define SCALE_CLAMP 4.1351665567423560f  /* log(1000/16) */

/* ---- workspace layout (bytes) ---- */
#define HIST_OFF   0u
#define HIST_BYTES (RREP * NBINS * 4u)            /* 2,097,152 */
#define MERGED_OFF (HIST_OFF + HIST_BYTES)        /* 65536*4 = 262,144 */
#define BLKSUM_OFF (MERGED_OFF + NBINS * 4u)      /* 64*4 = 256 */
#define CNT_OFF    (BLKSUM_OFF + 256u)
#define B_OFF      (CNT_OFF + 4u)
#define VW_OFF     (B_OFF + 4u)                   /* 16 u64 = 128 B (8-aligned) */
#define ZERO_END   (VW_OFF + 128u)
#define CAND_OFF   ZERO_END                       /* 8192 * 8 */
#define SC_OFF     (CAND_OFF + CAP * 8u)          /* M floats */
#define CLS_OFF    (SC_OFF + M_ANCH * 4u)         /* M ints */
#define SSC_OFF    (CLS_OFF + M_ANCH * 4u)        /* 1000 floats */
#define SCLS_OFF   (SSC_OFF + KTOP * 4u)          /* 1000 ints */
#define SUP_OFF    ((SCLS_OFF + KTOP * 4u + 15u) & ~15u)  /* 16000 u64, 16B-aligned */

__device__ __forceinline__ u32 fkey(float f) {
    u32 u = __float_as_uint(f);
    return (u & 0x80000000u) ? ~u : (u | 0x80000000u);
}

/* K1: block owns 64 anchors = 1280 contiguous float4s = 20 KB.
   Phase 1: 5 block-stride float4 loads (perfectly coalesced), per-float4 max
   -> LDS with stride-21 padding. Phase 2: 64 threads reduce 20 slots each. */
__global__ __launch_bounds__(256) void k_score(const float* __restrict__ cls_pred,
                                               float* __restrict__ sc_all,
                                               int* __restrict__ cls_all,
                                               u32* __restrict__ hist) {
    __shared__ float lm[64 * 21];
    __shared__ int   lc[64 * 21];
    int t = threadIdx.x;
    const float4* p = (const float4*)cls_pred + (size_t)blockIdx.x * 1280;
    float4 v0 = p[t];
    float4 v1 = p[t + 256];
    float4 v2 = p[t + 512];
    float4 v3 = p[t + 768];
    float4 v4 = p[t + 1024];
#pragma unroll
    for (int k = 0; k < 5; k++) {
        float4 v = (k == 0) ? v0 : (k == 1) ? v1 : (k == 2) ? v2 : (k == 3) ? v3 : v4;
        int f = t + 256 * k;      /* [0, 1280) */
        int a = f / 20;           /* local anchor [0, 64) */
        int s = f % 20;           /* slot [0, 20) */
        float mv = v.x; int mc = 0;
        if (v.y > mv) { mv = v.y; mc = 1; }
        if (v.z > mv) { mv = v.z; mc = 2; }
        if (v.w > mv) { mv = v.w; mc = 3; }
        lm[a * 21 + s] = mv;
        lc[a * 21 + s] = s * 4 + mc;
    }
    __syncthreads();
    if (t < 64) {
        float mv = -1e30f; int mc = 0;
#pragma unroll
        for (int s = 0; s < 20; s++) {
            float m = lm[t * 21 + s];
            int c = lc[t * 21 + s];
            if (m > mv) { mv = m; mc = c; }
        }
        int a = blockIdx.x * 64 + t;
        float sc = 1.0f / (1.0f + expf(-mv));
        sc_all[a] = sc;
        cls_all[a] = mc;
        float msk = (sc >= CONF_THRESH) ? sc : -1.0f;
        u32 u = fkey(msk);
        atomicAdd(&hist[((blockIdx.x & (RREP - 1)) << 16) + (u >> 16)], 1u);
    }
}

/* K2a: merge RREP histogram replicas (coalesced), emit per-1024-bin block sums */
__global__ __launch_bounds__(1024) void k_hsum(const u32* __restrict__ hist,
                                               u32* __restrict__ merged,
                                               u32* __restrict__ blksum) {
    __shared__ u32 red[1024];
    int t = threadIdx.x;
    int b = blockIdx.x * 1024 + t;
    u32 s = 0;
#pragma unroll
    for (int r = 0; r < RREP; r++) s += hist[r * NBINS + b];
    merged[b] = s;
    red[t] = s;
    __syncthreads();
    for (int off = 512; off > 0; off >>= 1) {
        if (t < off) red[t] += red[t + off];
        __syncthreads();
    }
    if (t == 0) blksum[blockIdx.x] = red[0];
}

/* K2b: find boundary bin B = max b with count(bins >= b) >= KTOP */
__global__ __launch_bounds__(1024) void k_boundary(const u32* __restrict__ merged,
                                                   const u32* __restrict__ blksum,
                                                   u32* __restrict__ outB) {
    __shared__ u32 bs[64];
    __shared__ u32 sj, sA;
    __shared__ u32 csum[1024];
    int t = threadIdx.x;
    if (t < 64) bs[t] = blksum[t];
    __syncthreads();
    if (t == 0) {
        u32 cum = 0; u32 j = 0; u32 Aj = 0;
        for (int b = 63; b >= 0; b--) {
            if (cum + bs[b] >= KTOP) { j = (u32)b; Aj = cum; break; }
            cum += bs[b];
        }
        sj = j; sA = Aj;
    }
    __syncthreads();
    u32 j = sj, Aj = sA;
    u32 h = merged[j * 1024 + t];
    csum[t] = h;
    __syncthreads();
    u32 v = h;
    for (int off = 1; off < 1024; off <<= 1) {
        u32 add = (t + off < 1024) ? csum[t + off] : 0u;
        __syncthreads();
        v += add;
        csum[t] = v;
        __syncthreads();
    }
    u32 above = (t == 1023) ? 0u : csum[t + 1];
    if (Aj + above < KTOP && Aj + above + h >= KTOP) outB[0] = j * 1024 + t;
}

/* K3: compact candidates (key bin >= B). Candidate SET is deterministic;
   order is not, but K4 sorts. CAP=8192 gives wide overflow margin. */
__global__ __launch_bounds__(256) void k_compact(const float* __restrict__ sc_all,
                                                 const u32* __restrict__ pB,
                                                 u32* __restrict__ counter,
                                                 u64* __restrict__ cand) {
    int i = blockIdx.x * 256 + threadIdx.x;
    if (i >= M_ANCH) return;
    u32 B = *pB;
    float s = sc_all[i];
    float m = (s >= CONF_THRESH) ? s : -1.0f;
    u32 u = fkey(m);
    if ((u >> 16) >= B) {
        u32 pos = atomicAdd(counter, 1u);
        if (pos < CAP) cand[pos] = ((u64)u << 32) | (u64)(0xFFFFFFFFu - (u32)i);
    }
}

/* K4: adaptive bitonic sort (P = next pow2 >= n, min 1024), top 1000, decode */
__global__ __launch_bounds__(1024) void k_select(const u64* __restrict__ cand,
                                                 const u32* __restrict__ counter,
                                                 const float* __restrict__ sc_all,
                                                 const int* __restrict__ cls_all,
                                                 const float* __restrict__ reg_pred,
                                                 const float* __restrict__ anchors,
                                                 float* __restrict__ out,
                                                 float* __restrict__ sel_sc,
                                                 int* __restrict__ sel_cls,
                                                 u64* __restrict__ valid_words) {
    __shared__ u64 keys[CAP];
    int t = threadIdx.x;
    u32 n = *counter;
    if (n > CAP) n = CAP;
    u32 P = 1024;
    while (P < n) P <<= 1;            /* P in {1024,...,8192} */
    for (u32 i = t; i < P; i += 1024) keys[i] = (i < n) ? cand[i] : 0ull;
    for (u32 k = 2; k <= P; k <<= 1) {
        for (u32 j = k >> 1; j > 0; j >>= 1) {
            __syncthreads();
            for (u32 i = t; i < P; i += 1024) {
                u32 ixj = i ^ j;
                if (ixj > i) {
                    u64 a = keys[i], b = keys[ixj];
                    bool desc = ((i & k) == 0);
                    if (desc ? (a < b) : (a > b)) { keys[i] = b; keys[ixj] = a; }
                }
            }
        }
    }
    __syncthreads();
    if (t < KTOP) {
        u64 key = keys[t];
        u32 idx = 0xFFFFFFFFu - (u32)(key & 0xFFFFFFFFull);
        if (idx >= M_ANCH) idx = 0;
        float s = sc_all[idx];
        int cl = cls_all[idx];
        float4 a = ((const float4*)anchors)[idx];
        float4 r = ((const float4*)reg_pred)[idx];
        float ox = fminf(fmaxf(r.x * a.z, -CTR_CLAMP), CTR_CLAMP);
        float oy = fminf(fmaxf(r.y * a.w, -CTR_CLAMP), CTR_CLAMP);
        float cx = a.x + ox, cy = a.y + oy;
        float ww = a.z * expf(fminf(r.z, SCALE_CLAMP));
        float hh = a.w * expf(fminf(r.w, SCALE_CLAMP));
        float4 box;
        box.x = cx - 0.5f * ww;
        box.y = cy - 0.5f * hh;
        box.z = cx + 0.5f * ww;
        box.w = cy + 0.5f * hh;
        ((float4*)out)[t] = box;                 /* boxes: out[0..3999] */
        out[5 * KTOP + t] = (float)cl;           /* classes: out[5000..5999] */
        sel_sc[t] = s;
        sel_cls[t] = cl;
        if (s >= CONF_THRESH) atomicOr(&valid_words[t >> 6], 1ull << (t & 63));
    }
}

/* K5: suppression matrix — one wave computes one 64-wide word via ballot */
__global__ __launch_bounds__(256) void k_supmat(const float* __restrict__ out,
                                                const int* __restrict__ sel_cls,
                                                u64* __restrict__ sup) {
    int wid = threadIdx.x >> 6;
    int lane = threadIdx.x & 63;
    int g = blockIdx.x * 4 + wid;          /* g in [0, 16000) */
    int i = g >> 4;
    int w = g & 15;
    int j = w * 64 + lane;
    int jc = (j < KTOP) ? j : (KTOP - 1);
    float4 bi = ((const float4*)out)[i];
    float4 bj = ((const float4*)out)[jc];
    int ci = sel_cls[i], cj = sel_cls[jc];
    float ai = (bi.z - bi.x) * (bi.w - bi.y);
    float aj = (bj.z - bj.x) * (bj.w - bj.y);
    float xx1 = fmaxf(bi.x, bj.x), yy1 = fmaxf(bi.y, bj.y);
    float xx2 = fminf(bi.z, bj.z), yy2 = fminf(bi.w, bj.w);
    float iw = fmaxf(1e-28f, xx2 - xx1), ih = fmaxf(1e-28f, yy2 - yy1);
    float inter = iw * ih;
    float iou = inter / (ai + aj - inter + 1e-14f);
    bool pred = (j < i) && (ci == cj) && (iou > NMS_THRESH);
    u64 bal = __ballot((int)pred);
    if (lane == 0) sup[g] = bal;
}

/* K6: greedy NMS, single wave, 16 blocks of 64 rows.
   Per block: parallel load of the 64x16 sup words (lane i = row 64b+i, 128
   contiguous bytes), prior-block suppression via AND with keep words in LDS,
   ONE ballot per block, then a fully-unrolled 64-step intra-block recurrence
   using inline v_readlane (off the dependent chain) — no wave-vote helpers,
   no memory ops, no waitcnt drains inside the serial chain. */
__global__ __launch_bounds__(64) void k_nms(const u64* __restrict__ sup,
                                            const u64* __restrict__ valid_words,
                                            const float* __restrict__ sel_sc,
                                            float* __restrict__ out) {
    __shared__ u64 keepA[16];
    int lane = threadIdx.x;
    if (lane < 16) keepA[lane] = 0ull;
    __syncthreads();

    for (int b = 0; b < 16; b++) {
        int row = b * 64 + lane;
        int rowc = (row < KTOP) ? row : (KTOP - 1);
        const ulonglong2* rp = (const ulonglong2*)(sup + (size_t)rowc * 16);
        ulonglong2 q0 = rp[0], q1 = rp[1], q2 = rp[2], q3 = rp[3];
        ulonglong2 q4 = rp[4], q5 = rp[5], q6 = rp[6], q7 = rp[7];
        u64 d = sup[(size_t)rowc * 16 + b];   /* intra-block word */
        u64 vm = valid_words[b];              /* wave-uniform scalar load */

        u64 acc = (q0.x & keepA[0])  | (q0.y & keepA[1])
                | (q1.x & keepA[2])  | (q1.y & keepA[3])
                | (q2.x & keepA[4])  | (q2.y & keepA[5])
                | (q3.x & keepA[6])  | (q3.y & keepA[7])
                | (q4.x & keepA[8])  | (q4.y & keepA[9])
                | (q5.x & keepA[10]) | (q5.y & keepA[11])
                | (q6.x & keepA[12]) | (q6.y & keepA[13])
                | (q7.x & keepA[14]) | (q7.y & keepA[15]);
        u64 premask = __ballot(acc != 0ull);
        u64 eligible = vm & ~premask;

        u32 dlo = (u32)d, dhi = (u32)(d >> 32);
        u64 kb = 0ull;
#pragma unroll
        for (int j = 0; j < 64; j++) {
            u32 djl = __builtin_amdgcn_readlane(dlo, j);
            u32 djh = __builtin_amdgcn_readlane(dhi, j);
            u64 dj = ((u64)djh << 32) | (u64)djl;
            bool kj = (((eligible >> j) & 1ull) != 0ull) && ((dj & kb) == 0ull);
            kb |= ((u64)(kj ? 1u : 0u)) << j;
        }
        if (lane == 0) keepA[b] = kb;
        __syncthreads();
    }

    for (int t = lane; t < KTOP; t += 64) {
        int kb = (int)((keepA[t >> 6] >> (t & 63)) & 1ull);
        float s = sel_sc[t];
        out[4 * KTOP + t] = kb ? s : 0.0f;   /* scores*keep: out[4000..4999] */
        out[6 * KTOP + t] = (float)kb;       /* keep:        out[6000..6999] */
    }
}

extern "C" void kernel_launch(void* const* d_in, const int* in_sizes, int n_in,
                              void* d_out, int out_size, void* d_ws, size_t ws_size,
                              hipStream_t stream) {
    const float* cls_pred = (const float*)d_in[0];
    const float* reg_pred = (const float*)d_in[1];
    const float* anchors  = (const float*)d_in[2];
    float* out = (float*)d_out;
    char* ws = (char*)d_ws;

    u32* hist     = (u32*)(ws + HIST_OFF);
    u32* merged   = (u32*)(ws + MERGED_OFF);
    u32* blksum   = (u32*)(ws + BLKSUM_OFF);
    u32* counter  = (u32*)(ws + CNT_OFF);
    u32* pB       = (u32*)(ws + B_OFF);
    u64* vwords   = (u64*)(ws + VW_OFF);
    u64* cand     = (u64*)(ws + CAND_OFF);
    float* sc_all = (float*)(ws + SC_OFF);
    int* cls_all  = (int*)(ws + CLS_OFF);
    float* sel_sc = (float*)(ws + SSC_OFF);
    int* sel_cls  = (int*)(ws + SCLS_OFF);
    u64* sup      = (u64*)(ws + SUP_OFF);

    hipMemsetAsync(d_ws, 0, ZERO_END, stream);

    int nbs = M_ANCH / 64;            /* 5625 blocks, 64 anchors each */
    int nbc = (M_ANCH + 255) / 256;
    k_score<<<nbs, 256, 0, stream>>>(cls_pred, sc_all, cls_all, hist);
    k_hsum<<<NBINS / 1024, 1024, 0, stream>>>(hist, merged, blksum);
    k_boundary<<<1, 1024, 0, stream>>>(merged, blksum, pB);
    k_compact<<<nbc, 256, 0, stream>>>(sc_all, pB, counter, cand);
    k_select<<<1, 1024, 0, stream>>>(cand, counter, sc_all, cls_all, reg_pred,
                                     anchors, out, sel_sc, sel_cls, vwords);
    k_supmat<<<(KTOP * 16) / 4, 256, 0, stream>>>(out, sel_cls, sup);
    k_nms<<<1, 64, 0, stream>>>(sup, vwords, sel_sc, out);
}

// Round 7
// 318.462 us; speedup vs baseline: 1.1140x; 1.0057x over previous
//
#include <hip/hip_runtime.h>
#include <math.h>

typedef unsigned long long u64;
typedef unsigned int u32;

#define M_ANCH 360000
#define NCLS 80
#define KTOP 1000
#define CAP 8192
#define NBINS 65536
#define RREP 8
#define CONF_THRESH 0.05f
#define NMS_THRESH 0.6f
#define CTR_CLAMP 32.0f
#define SCALE_CLAMP 4.1351665567423560f  /* log(1000/16) */

/* ---- workspace layout (bytes): zeroed region first, write-before-read after */
#define HIST_OFF   0u
#define HIST_BYTES (RREP * NBINS * 4u)            /* 2,097,152 */
#define CNT_OFF    (HIST_OFF + HIST_BYTES)
#define B_OFF      (CNT_OFF + 4u)
#define VW_OFF     (B_OFF + 4u + 8u)              /* pad to 8B align: 2,097,168 */
#define ZERO_END   (VW_OFF + 128u)                /* ~2.097 MB zeroed */
#define MERGED_OFF ZERO_END                       /* 65536*4, written by k_hsum */
#define BLKSUM_OFF (MERGED_OFF + NBINS * 4u)      /* 64*4 */
#define CAND_OFF   (BLKSUM_OFF + 256u)            /* 8192*8 */
#define SC_OFF     (CAND_OFF + CAP * 8u)          /* M floats */
#define CLS_OFF    (SC_OFF + M_ANCH * 4u)         /* M ints */
#define SSC_OFF    (CLS_OFF + M_ANCH * 4u)        /* 1000 floats */
#define SCLS_OFF   (SSC_OFF + KTOP * 4u)          /* 1000 ints */
#define SUP_OFF    ((SCLS_OFF + KTOP * 4u + 15u) & ~15u)  /* 16000 u64, 16B-aligned */

__device__ __forceinline__ u32 fkey(float f) {
    u32 u = __float_as_uint(f);
    return (u & 0x80000000u) ? ~u : (u | 0x80000000u);
}

/* K1: block owns 64 anchors = 1280 contiguous float4s = 20 KB.
   Phase 1: 5 block-stride float4 loads, ALL issued before any use
   (sched_barrier pins them; launch_bounds(256,8) gives VGPR room so the
   compiler cannot sink loads into their consumers — round-6 showed VGPR=16
   with serialized load->use chains at 67 us).
   Phase 2: LDS transpose (stride 21), 64 threads reduce 20 slots each. */
__global__ __launch_bounds__(256, 8) void k_score(const float* __restrict__ cls_pred,
                                                  float* __restrict__ sc_all,
                                                  int* __restrict__ cls_all,
                                                  u32* __restrict__ hist) {
    __shared__ float lm[64 * 21];
    __shared__ int   lc[64 * 21];
    int t = threadIdx.x;
    const float4* p = (const float4*)cls_pred + (size_t)blockIdx.x * 1280;
    float4 v0 = p[t];
    float4 v1 = p[t + 256];
    float4 v2 = p[t + 512];
    float4 v3 = p[t + 768];
    float4 v4 = p[t + 1024];
    __builtin_amdgcn_sched_barrier(0);   /* keep all 5 loads above, in flight */
#pragma unroll
    for (int k = 0; k < 5; k++) {
        float4 v = (k == 0) ? v0 : (k == 1) ? v1 : (k == 2) ? v2 : (k == 3) ? v3 : v4;
        int f = t + 256 * k;      /* [0, 1280) */
        int a = f / 20;           /* local anchor [0, 64) */
        int s = f % 20;           /* slot [0, 20) */
        float mv = v.x; int mc = 0;
        if (v.y > mv) { mv = v.y; mc = 1; }
        if (v.z > mv) { mv = v.z; mc = 2; }
        if (v.w > mv) { mv = v.w; mc = 3; }
        lm[a * 21 + s] = mv;
        lc[a * 21 + s] = s * 4 + mc;
    }
    __syncthreads();
    if (t < 64) {
        float mv = -1e30f; int mc = 0;
#pragma unroll
        for (int s = 0; s < 20; s++) {
            float m = lm[t * 21 + s];
            int c = lc[t * 21 + s];
            if (m > mv) { mv = m; mc = c; }
        }
        int a = blockIdx.x * 64 + t;
        float sc = 1.0f / (1.0f + expf(-mv));
        sc_all[a] = sc;
        cls_all[a] = mc;
        float msk = (sc >= CONF_THRESH) ? sc : -1.0f;
        u32 u = fkey(msk);
        atomicAdd(&hist[((blockIdx.x & (RREP - 1)) << 16) + (u >> 16)], 1u);
    }
}

/* K2a: merge RREP histogram replicas (coalesced), emit per-1024-bin block sums */
__global__ __launch_bounds__(1024) void k_hsum(const u32* __restrict__ hist,
                                               u32* __restrict__ merged,
                                               u32* __restrict__ blksum) {
    __shared__ u32 red[1024];
    int t = threadIdx.x;
    int b = blockIdx.x * 1024 + t;
    u32 s = 0;
#pragma unroll
    for (int r = 0; r < RREP; r++) s += hist[r * NBINS + b];
    merged[b] = s;
    red[t] = s;
    __syncthreads();
    for (int off = 512; off > 0; off >>= 1) {
        if (t < off) red[t] += red[t + off];
        __syncthreads();
    }
    if (t == 0) blksum[blockIdx.x] = red[0];
}

/* K2b: find boundary bin B = max b with count(bins >= b) >= KTOP */
__global__ __launch_bounds__(1024) void k_boundary(const u32* __restrict__ merged,
                                                   const u32* __restrict__ blksum,
                                                   u32* __restrict__ outB) {
    __shared__ u32 bs[64];
    __shared__ u32 sj, sA;
    __shared__ u32 csum[1024];
    int t = threadIdx.x;
    if (t < 64) bs[t] = blksum[t];
    __syncthreads();
    if (t == 0) {
        u32 cum = 0; u32 j = 0; u32 Aj = 0;
        for (int b = 63; b >= 0; b--) {
            if (cum + bs[b] >= KTOP) { j = (u32)b; Aj = cum; break; }
            cum += bs[b];
        }
        sj = j; sA = Aj;
    }
    __syncthreads();
    u32 j = sj, Aj = sA;
    u32 h = merged[j * 1024 + t];
    csum[t] = h;
    __syncthreads();
    u32 v = h;
    for (int off = 1; off < 1024; off <<= 1) {
        u32 add = (t + off < 1024) ? csum[t + off] : 0u;
        __syncthreads();
        v += add;
        csum[t] = v;
        __syncthreads();
    }
    u32 above = (t == 1023) ? 0u : csum[t + 1];
    if (Aj + above < KTOP && Aj + above + h >= KTOP) outB[0] = j * 1024 + t;
}

/* K3: compact candidates (key bin >= B). Candidate SET is deterministic;
   order is not, but K4 sorts. CAP=8192 gives wide overflow margin. */
__global__ __launch_bounds__(256) void k_compact(const float* __restrict__ sc_all,
                                                 const u32* __restrict__ pB,
                                                 u32* __restrict__ counter,
                                                 u64* __restrict__ cand) {
    int i = blockIdx.x * 256 + threadIdx.x;
    if (i >= M_ANCH) return;
    u32 B = *pB;
    float s = sc_all[i];
    float m = (s >= CONF_THRESH) ? s : -1.0f;
    u32 u = fkey(m);
    if ((u >> 16) >= B) {
        u32 pos = atomicAdd(counter, 1u);
        if (pos < CAP) cand[pos] = ((u64)u << 32) | (u64)(0xFFFFFFFFu - (u32)i);
    }
}

/* K4: adaptive bitonic sort (P = next pow2 >= n, min 1024), top 1000, decode */
__global__ __launch_bounds__(1024) void k_select(const u64* __restrict__ cand,
                                                 const u32* __restrict__ counter,
                                                 const float* __restrict__ sc_all,
                                                 const int* __restrict__ cls_all,
                                                 const float* __restrict__ reg_pred,
                                                 const float* __restrict__ anchors,
                                                 float* __restrict__ out,
                                                 float* __restrict__ sel_sc,
                                                 int* __restrict__ sel_cls,
                                                 u64* __restrict__ valid_words) {
    __shared__ u64 keys[CAP];
    int t = threadIdx.x;
    u32 n = *counter;
    if (n > CAP) n = CAP;
    u32 P = 1024;
    while (P < n) P <<= 1;            /* P in {1024,...,8192} */
    for (u32 i = t; i < P; i += 1024) keys[i] = (i < n) ? cand[i] : 0ull;
    for (u32 k = 2; k <= P; k <<= 1) {
        for (u32 j = k >> 1; j > 0; j >>= 1) {
            __syncthreads();
            for (u32 i = t; i < P; i += 1024) {
                u32 ixj = i ^ j;
                if (ixj > i) {
                    u64 a = keys[i], b = keys[ixj];
                    bool desc = ((i & k) == 0);
                    if (desc ? (a < b) : (a > b)) { keys[i] = b; keys[ixj] = a; }
                }
            }
        }
    }
    __syncthreads();
    if (t < KTOP) {
        u64 key = keys[t];
        u32 idx = 0xFFFFFFFFu - (u32)(key & 0xFFFFFFFFull);
        if (idx >= M_ANCH) idx = 0;
        float s = sc_all[idx];
        int cl = cls_all[idx];
        float4 a = ((const float4*)anchors)[idx];
        float4 r = ((const float4*)reg_pred)[idx];
        float ox = fminf(fmaxf(r.x * a.z, -CTR_CLAMP), CTR_CLAMP);
        float oy = fminf(fmaxf(r.y * a.w, -CTR_CLAMP), CTR_CLAMP);
        float cx = a.x + ox, cy = a.y + oy;
        float ww = a.z * expf(fminf(r.z, SCALE_CLAMP));
        float hh = a.w * expf(fminf(r.w, SCALE_CLAMP));
        float4 box;
        box.x = cx - 0.5f * ww;
        box.y = cy - 0.5f * hh;
        box.z = cx + 0.5f * ww;
        box.w = cy + 0.5f * hh;
        ((float4*)out)[t] = box;                 /* boxes: out[0..3999] */
        out[5 * KTOP + t] = (float)cl;           /* classes: out[5000..5999] */
        sel_sc[t] = s;
        sel_cls[t] = cl;
        if (s >= CONF_THRESH) atomicOr(&valid_words[t >> 6], 1ull << (t & 63));
    }
}

/* K5: suppression matrix — one wave computes one 64-wide word via ballot */
__global__ __launch_bounds__(256) void k_supmat(const float* __restrict__ out,
                                                const int* __restrict__ sel_cls,
                                                u64* __restrict__ sup) {
    int wid = threadIdx.x >> 6;
    int lane = threadIdx.x & 63;
    int g = blockIdx.x * 4 + wid;          /* g in [0, 16000) */
    int i = g >> 4;
    int w = g & 15;
    int j = w * 64 + lane;
    int jc = (j < KTOP) ? j : (KTOP - 1);
    float4 bi = ((const float4*)out)[i];
    float4 bj = ((const float4*)out)[jc];
    int ci = sel_cls[i], cj = sel_cls[jc];
    float ai = (bi.z - bi.x) * (bi.w - bi.y);
    float aj = (bj.z - bj.x) * (bj.w - bj.y);
    float xx1 = fmaxf(bi.x, bj.x), yy1 = fmaxf(bi.y, bj.y);
    float xx2 = fminf(bi.z, bj.z), yy2 = fminf(bi.w, bj.w);
    float iw = fmaxf(1e-28f, xx2 - xx1), ih = fmaxf(1e-28f, yy2 - yy1);
    float inter = iw * ih;
    float iou = inter / (ai + aj - inter + 1e-14f);
    bool pred = (j < i) && (ci == cj) && (iou > NMS_THRESH);
    u64 bal = __ballot((int)pred);
    if (lane == 0) sup[g] = bal;
}

/* K6: greedy NMS, single wave, 16 blocks of 64 rows. Parallel row loads,
   one ballot per 64-row block, fully-unrolled readlane recurrence — no
   wave-vote helpers or memory ops inside the serial chain. */
__global__ __launch_bounds__(64) void k_nms(const u64* __restrict__ sup,
                                            const u64* __restrict__ valid_words,
                                            const float* __restrict__ sel_sc,
                                            float* __restrict__ out) {
    __shared__ u64 keepA[16];
    int lane = threadIdx.x;
    if (lane < 16) keepA[lane] = 0ull;
    __syncthreads();

    for (int b = 0; b < 16; b++) {
        int row = b * 64 + lane;
        int rowc = (row < KTOP) ? row : (KTOP - 1);
        const ulonglong2* rp = (const ulonglong2*)(sup + (size_t)rowc * 16);
        ulonglong2 q0 = rp[0], q1 = rp[1], q2 = rp[2], q3 = rp[3];
        ulonglong2 q4 = rp[4], q5 = rp[5], q6 = rp[6], q7 = rp[7];
        u64 d = sup[(size_t)rowc * 16 + b];   /* intra-block word */
        u64 vm = valid_words[b];              /* wave-uniform scalar load */

        u64 acc = (q0.x & keepA[0])  | (q0.y & keepA[1])
                | (q1.x & keepA[2])  | (q1.y & keepA[3])
                | (q2.x & keepA[4])  | (q2.y & keepA[5])
                | (q3.x & keepA[6])  | (q3.y & keepA[7])
                | (q4.x & keepA[8])  | (q4.y & keepA[9])
                | (q5.x & keepA[10]) | (q5.y & keepA[11])
                | (q6.x & keepA[12]) | (q6.y & keepA[13])
                | (q7.x & keepA[14]) | (q7.y & keepA[15]);
        u64 premask = __ballot(acc != 0ull);
        u64 eligible = vm & ~premask;

        u32 dlo = (u32)d, dhi = (u32)(d >> 32);
        u64 kb = 0ull;
#pragma unroll
        for (int j = 0; j < 64; j++) {
            u32 djl = __builtin_amdgcn_readlane(dlo, j);
            u32 djh = __builtin_amdgcn_readlane(dhi, j);
            u64 dj = ((u64)djh << 32) | (u64)djl;
            bool kj = (((eligible >> j) & 1ull) != 0ull) && ((dj & kb) == 0ull);
            kb |= ((u64)(kj ? 1u : 0u)) << j;
        }
        if (lane == 0) keepA[b] = kb;
        __syncthreads();
    }

    for (int t = lane; t < KTOP; t += 64) {
        int kb = (int)((keepA[t >> 6] >> (t & 63)) & 1ull);
        float s = sel_sc[t];
        out[4 * KTOP + t] = kb ? s : 0.0f;   /* scores*keep: out[4000..4999] */
        out[6 * KTOP + t] = (float)kb;       /* keep:        out[6000..6999] */
    }
}

extern "C" void kernel_launch(void* const* d_in, const int* in_sizes, int n_in,
                              void* d_out, int out_size, void* d_ws, size_t ws_size,
                              hipStream_t stream) {
    const float* cls_pred = (const float*)d_in[0];
    const float* reg_pred = (const float*)d_in[1];
    const float* anchors  = (const float*)d_in[2];
    float* out = (float*)d_out;
    char* ws = (char*)d_ws;

    u32* hist     = (u32*)(ws + HIST_OFF);
    u32* counter  = (u32*)(ws + CNT_OFF);
    u32* pB       = (u32*)(ws + B_OFF);
    u64* vwords   = (u64*)(ws + VW_OFF);
    u32* merged   = (u32*)(ws + MERGED_OFF);
    u32* blksum   = (u32*)(ws + BLKSUM_OFF);
    u64* cand     = (u64*)(ws + CAND_OFF);
    float* sc_all = (float*)(ws + SC_OFF);
    int* cls_all  = (int*)(ws + CLS_OFF);
    float* sel_sc = (float*)(ws + SSC_OFF);
    int* sel_cls  = (int*)(ws + SCLS_OFF);
    u64* sup      = (u64*)(ws + SUP_OFF);

    hipMemsetAsync(d_ws, 0, ZERO_END, stream);

    int nbs = M_ANCH / 64;            /* 5625 blocks, 64 anchors each */
    int nbc = (M_ANCH + 255) / 256;
    k_score<<<nbs, 256, 0, stream>>>(cls_pred, sc_all, cls_all, hist);
    k_hsum<<<NBINS / 1024, 1024, 0, stream>>>(hist, merged, blksum);
    k_boundary<<<1, 1024, 0, stream>>>(merged, blksum, pB);
    k_compact<<<nbc, 256, 0, stream>>>(sc_all, pB, counter, cand);
    k_select<<<1, 1024, 0, stream>>>(cand, counter, sc_all, cls_all, reg_pred,
                                     anchors, out, sel_sc, sel_cls, vwords);
    k_supmat<<<(KTOP * 16) / 4, 256, 0, stream>>>(out, sel_cls, sup);
    k_nms<<<1, 64, 0, stream>>>(sup, vwords, sel_sc, out);
}

// Round 8
// 315.337 us; speedup vs baseline: 1.1251x; 1.0099x over previous
//
#include <hip/hip_runtime.h>
#include <math.h>

typedef unsigned long long u64;
typedef unsigned int u32;

#define M_ANCH 360000
#define NCLS 80
#define KTOP 1000
#define CAP 8192
#define NBINS 65536
#define RREP 8
#define CONF_THRESH 0.05f
#define NMS_THRESH 0.6f
#define CTR_CLAMP 32.0f
#define SCALE_CLAMP 4.1351665567423560f  /* log(1000/16) */

#define AS1 __attribute__((address_space(1)))
#define AS3 __attribute__((address_space(3)))

/* ---- workspace layout (bytes): zeroed region first, write-before-read after */
#define HIST_OFF   0u
#define HIST_BYTES (RREP * NBINS * 4u)            /* 2,097,152 */
#define CNT_OFF    (HIST_OFF + HIST_BYTES)
#define B_OFF      (CNT_OFF + 4u)
#define VW_OFF     (B_OFF + 4u + 8u)              /* pad to 8B align */
#define ZERO_END   (VW_OFF + 128u)                /* ~2.097 MB zeroed */
#define MERGED_OFF ZERO_END                       /* 65536*4, written by k_hsum */
#define BLKSUM_OFF (MERGED_OFF + NBINS * 4u)      /* 64*4 */
#define CAND_OFF   (BLKSUM_OFF + 256u)            /* 8192*8 */
#define SC_OFF     (CAND_OFF + CAP * 8u)          /* M floats */
#define CLS_OFF    (SC_OFF + M_ANCH * 4u)         /* M ints */
#define SSC_OFF    (CLS_OFF + M_ANCH * 4u)        /* 1000 floats */
#define SCLS_OFF   (SSC_OFF + KTOP * 4u)          /* 1000 ints */
#define SUP_OFF    ((SCLS_OFF + KTOP * 4u + 15u) & ~15u)  /* 16000 u64, 16B-aligned */

__device__ __forceinline__ u32 fkey(float f) {
    u32 u = __float_as_uint(f);
    return (u & 0x80000000u) ? ~u : (u | 0x80000000u);
}

/* K1: block owns 64 anchors = 1280 contiguous float4s = 20 KB.
   Phase A: stage to LDS via global_load_lds width=16 DMA — no VGPR round
   trip, so the compiler cannot serialize the loads (rounds 3/6/7 showed the
   VMEM->VGPR path stuck at ~1.8 TB/s regardless of scheduling hints). One
   vmcnt drain at the barrier.
   Phase B: 64 threads reduce 20 float4s each straight from LDS; rotated
   start (t&7) spreads lanes across all 8 16B bank groups; explicit
   (==, lower class) tie-break restores argmax-first semantics. */
__global__ __launch_bounds__(256) void k_score(const float* __restrict__ cls_pred,
                                               float* __restrict__ sc_all,
                                               int* __restrict__ cls_all,
                                               u32* __restrict__ hist) {
    __shared__ float4 stage[1280];
    int t = threadIdx.x;
    const float4* gp = (const float4*)cls_pred + (size_t)blockIdx.x * 1280;
#pragma unroll
    for (int k = 0; k < 5; k++) {
        int f = t + 256 * k;
        __builtin_amdgcn_global_load_lds((AS1 void*)(gp + f),
                                         (AS3 void*)(stage + f), 16, 0, 0);
    }
    __syncthreads();   /* drains the DMA (vmcnt(0) before s_barrier) */

    if (t < 64) {
        const float4* av = stage + t * 20;
        float mv = -1e30f; int mc = 0;
        int k0 = t & 7;
#pragma unroll
        for (int i = 0; i < 20; i++) {
            int k = k0 + i;
            if (k >= 20) k -= 20;
            float4 v = av[k];
            float lm_ = v.x; int lc_ = 4 * k;
            if (v.y > lm_) { lm_ = v.y; lc_ = 4 * k + 1; }
            if (v.z > lm_) { lm_ = v.z; lc_ = 4 * k + 2; }
            if (v.w > lm_) { lm_ = v.w; lc_ = 4 * k + 3; }
            if (lm_ > mv || (lm_ == mv && lc_ < mc)) { mv = lm_; mc = lc_; }
        }
        int a = blockIdx.x * 64 + t;
        float sc = 1.0f / (1.0f + expf(-mv));
        sc_all[a] = sc;
        cls_all[a] = mc;
        float msk = (sc >= CONF_THRESH) ? sc : -1.0f;
        u32 u = fkey(msk);
        atomicAdd(&hist[((blockIdx.x & (RREP - 1)) << 16) + (u >> 16)], 1u);
    }
}

/* K2a: merge RREP histogram replicas (coalesced), emit per-1024-bin block sums */
__global__ __launch_bounds__(1024) void k_hsum(const u32* __restrict__ hist,
                                               u32* __restrict__ merged,
                                               u32* __restrict__ blksum) {
    __shared__ u32 red[1024];
    int t = threadIdx.x;
    int b = blockIdx.x * 1024 + t;
    u32 s = 0;
#pragma unroll
    for (int r = 0; r < RREP; r++) s += hist[r * NBINS + b];
    merged[b] = s;
    red[t] = s;
    __syncthreads();
    for (int off = 512; off > 0; off >>= 1) {
        if (t < off) red[t] += red[t + off];
        __syncthreads();
    }
    if (t == 0) blksum[blockIdx.x] = red[0];
}

/* K2b: find boundary bin B = max b with count(bins >= b) >= KTOP */
__global__ __launch_bounds__(1024) void k_boundary(const u32* __restrict__ merged,
                                                   const u32* __restrict__ blksum,
                                                   u32* __restrict__ outB) {
    __shared__ u32 bs[64];
    __shared__ u32 sj, sA;
    __shared__ u32 csum[1024];
    int t = threadIdx.x;
    if (t < 64) bs[t] = blksum[t];
    __syncthreads();
    if (t == 0) {
        u32 cum = 0; u32 j = 0; u32 Aj = 0;
        for (int b = 63; b >= 0; b--) {
            if (cum + bs[b] >= KTOP) { j = (u32)b; Aj = cum; break; }
            cum += bs[b];
        }
        sj = j; sA = Aj;
    }
    __syncthreads();
    u32 j = sj, Aj = sA;
    u32 h = merged[j * 1024 + t];
    csum[t] = h;
    __syncthreads();
    u32 v = h;
    for (int off = 1; off < 1024; off <<= 1) {
        u32 add = (t + off < 1024) ? csum[t + off] : 0u;
        __syncthreads();
        v += add;
        csum[t] = v;
        __syncthreads();
    }
    u32 above = (t == 1023) ? 0u : csum[t + 1];
    if (Aj + above < KTOP && Aj + above + h >= KTOP) outB[0] = j * 1024 + t;
}

/* K3: compact candidates (key bin >= B). Candidate SET is deterministic;
   order is not, but K4 sorts. CAP=8192 gives wide overflow margin. */
__global__ __launch_bounds__(256) void k_compact(const float* __restrict__ sc_all,
                                                 const u32* __restrict__ pB,
                                                 u32* __restrict__ counter,
                                                 u64* __restrict__ cand) {
    int i = blockIdx.x * 256 + threadIdx.x;
    if (i >= M_ANCH) return;
    u32 B = *pB;
    float s = sc_all[i];
    float m = (s >= CONF_THRESH) ? s : -1.0f;
    u32 u = fkey(m);
    if ((u >> 16) >= B) {
        u32 pos = atomicAdd(counter, 1u);
        if (pos < CAP) cand[pos] = ((u64)u << 32) | (u64)(0xFFFFFFFFu - (u32)i);
    }
}

/* K4: adaptive bitonic sort (P = next pow2 >= n, min 1024), top 1000, decode */
__global__ __launch_bounds__(1024) void k_select(const u64* __restrict__ cand,
                                                 const u32* __restrict__ counter,
                                                 const float* __restrict__ sc_all,
                                                 const int* __restrict__ cls_all,
                                                 const float* __restrict__ reg_pred,
                                                 const float* __restrict__ anchors,
                                                 float* __restrict__ out,
                                                 float* __restrict__ sel_sc,
                                                 int* __restrict__ sel_cls,
                                                 u64* __restrict__ valid_words) {
    __shared__ u64 keys[CAP];
    int t = threadIdx.x;
    u32 n = *counter;
    if (n > CAP) n = CAP;
    u32 P = 1024;
    while (P < n) P <<= 1;            /* P in {1024,...,8192} */
    for (u32 i = t; i < P; i += 1024) keys[i] = (i < n) ? cand[i] : 0ull;
    for (u32 k = 2; k <= P; k <<= 1) {
        for (u32 j = k >> 1; j > 0; j >>= 1) {
            __syncthreads();
            for (u32 i = t; i < P; i += 1024) {
                u32 ixj = i ^ j;
                if (ixj > i) {
                    u64 a = keys[i], b = keys[ixj];
                    bool desc = ((i & k) == 0);
                    if (desc ? (a < b) : (a > b)) { keys[i] = b; keys[ixj] = a; }
                }
            }
        }
    }
    __syncthreads();
    if (t < KTOP) {
        u64 key = keys[t];
        u32 idx = 0xFFFFFFFFu - (u32)(key & 0xFFFFFFFFull);
        if (idx >= M_ANCH) idx = 0;
        float s = sc_all[idx];
        int cl = cls_all[idx];
        float4 a = ((const float4*)anchors)[idx];
        float4 r = ((const float4*)reg_pred)[idx];
        float ox = fminf(fmaxf(r.x * a.z, -CTR_CLAMP), CTR_CLAMP);
        float oy = fminf(fmaxf(r.y * a.w, -CTR_CLAMP), CTR_CLAMP);
        float cx = a.x + ox, cy = a.y + oy;
        float ww = a.z * expf(fminf(r.z, SCALE_CLAMP));
        float hh = a.w * expf(fminf(r.w, SCALE_CLAMP));
        float4 box;
        box.x = cx - 0.5f * ww;
        box.y = cy - 0.5f * hh;
        box.z = cx + 0.5f * ww;
        box.w = cy + 0.5f * hh;
        ((float4*)out)[t] = box;                 /* boxes: out[0..3999] */
        out[5 * KTOP + t] = (float)cl;           /* classes: out[5000..5999] */
        sel_sc[t] = s;
        sel_cls[t] = cl;
        if (s >= CONF_THRESH) atomicOr(&valid_words[t >> 6], 1ull << (t & 63));
    }
}

/* K5: suppression matrix — one wave computes one 64-wide word via ballot */
__global__ __launch_bounds__(256) void k_supmat(const float* __restrict__ out,
                                                const int* __restrict__ sel_cls,
                                                u64* __restrict__ sup) {
    int wid = threadIdx.x >> 6;
    int lane = threadIdx.x & 63;
    int g = blockIdx.x * 4 + wid;          /* g in [0, 16000) */
    int i = g >> 4;
    int w = g & 15;
    int j = w * 64 + lane;
    int jc = (j < KTOP) ? j : (KTOP - 1);
    float4 bi = ((const float4*)out)[i];
    float4 bj = ((const float4*)out)[jc];
    int ci = sel_cls[i], cj = sel_cls[jc];
    float ai = (bi.z - bi.x) * (bi.w - bi.y);
    float aj = (bj.z - bj.x) * (bj.w - bj.y);
    float xx1 = fmaxf(bi.x, bj.x), yy1 = fmaxf(bi.y, bj.y);
    float xx2 = fminf(bi.z, bj.z), yy2 = fminf(bi.w, bj.w);
    float iw = fmaxf(1e-28f, xx2 - xx1), ih = fmaxf(1e-28f, yy2 - yy1);
    float inter = iw * ih;
    float iou = inter / (ai + aj - inter + 1e-14f);
    bool pred = (j < i) && (ci == cj) && (iou > NMS_THRESH);
    u64 bal = __ballot((int)pred);
    if (lane == 0) sup[g] = bal;
}

/* K6: greedy NMS, single wave, 16 blocks of 64 rows. Parallel row loads,
   one ballot per 64-row block, fully-unrolled readlane recurrence — no
   wave-vote helpers or memory ops inside the serial chain. */
__global__ __launch_bounds__(64) void k_nms(const u64* __restrict__ sup,
                                            const u64* __restrict__ valid_words,
                                            const float* __restrict__ sel_sc,
                                            float* __restrict__ out) {
    __shared__ u64 keepA[16];
    int lane = threadIdx.x;
    if (lane < 16) keepA[lane] = 0ull;
    __syncthreads();

    for (int b = 0; b < 16; b++) {
        int row = b * 64 + lane;
        int rowc = (row < KTOP) ? row : (KTOP - 1);
        const ulonglong2* rp = (const ulonglong2*)(sup + (size_t)rowc * 16);
        ulonglong2 q0 = rp[0], q1 = rp[1], q2 = rp[2], q3 = rp[3];
        ulonglong2 q4 = rp[4], q5 = rp[5], q6 = rp[6], q7 = rp[7];
        u64 d = sup[(size_t)rowc * 16 + b];   /* intra-block word */
        u64 vm = valid_words[b];              /* wave-uniform scalar load */

        u64 acc = (q0.x & keepA[0])  | (q0.y & keepA[1])
                | (q1.x & keepA[2])  | (q1.y & keepA[3])
                | (q2.x & keepA[4])  | (q2.y & keepA[5])
                | (q3.x & keepA[6])  | (q3.y & keepA[7])
                | (q4.x & keepA[8])  | (q4.y & keepA[9])
                | (q5.x & keepA[10]) | (q5.y & keepA[11])
                | (q6.x & keepA[12]) | (q6.y & keepA[13])
                | (q7.x & keepA[14]) | (q7.y & keepA[15]);
        u64 premask = __ballot(acc != 0ull);
        u64 eligible = vm & ~premask;

        u32 dlo = (u32)d, dhi = (u32)(d >> 32);
        u64 kb = 0ull;
#pragma unroll
        for (int j = 0; j < 64; j++) {
            u32 djl = __builtin_amdgcn_readlane(dlo, j);
            u32 djh = __builtin_amdgcn_readlane(dhi, j);
            u64 dj = ((u64)djh << 32) | (u64)djl;
            bool kj = (((eligible >> j) & 1ull) != 0ull) && ((dj & kb) == 0ull);
            kb |= ((u64)(kj ? 1u : 0u)) << j;
        }
        if (lane == 0) keepA[b] = kb;
        __syncthreads();
    }

    for (int t = lane; t < KTOP; t += 64) {
        int kb = (int)((keepA[t >> 6] >> (t & 63)) & 1ull);
        float s = sel_sc[t];
        out[4 * KTOP + t] = kb ? s : 0.0f;   /* scores*keep: out[4000..4999] */
        out[6 * KTOP + t] = (float)kb;       /* keep:        out[6000..6999] */
    }
}

extern "C" void kernel_launch(void* const* d_in, const int* in_sizes, int n_in,
                              void* d_out, int out_size, void* d_ws, size_t ws_size,
                              hipStream_t stream) {
    const float* cls_pred = (const float*)d_in[0];
    const float* reg_pred = (const float*)d_in[1];
    const float* anchors  = (const float*)d_in[2];
    float* out = (float*)d_out;
    char* ws = (char*)d_ws;

    u32* hist     = (u32*)(ws + HIST_OFF);
    u32* counter  = (u32*)(ws + CNT_OFF);
    u32* pB       = (u32*)(ws + B_OFF);
    u64* vwords   = (u64*)(ws + VW_OFF);
    u32* merged   = (u32*)(ws + MERGED_OFF);
    u32* blksum   = (u32*)(ws + BLKSUM_OFF);
    u64* cand     = (u64*)(ws + CAND_OFF);
    float* sc_all = (float*)(ws + SC_OFF);
    int* cls_all  = (int*)(ws + CLS_OFF);
    float* sel_sc = (float*)(ws + SSC_OFF);
    int* sel_cls  = (int*)(ws + SCLS_OFF);
    u64* sup      = (u64*)(ws + SUP_OFF);

    hipMemsetAsync(d_ws, 0, ZERO_END, stream);

    int nbs = M_ANCH / 64;            /* 5625 blocks, 64 anchors each */
    int nbc = (M_ANCH + 255) / 256;
    k_score<<<nbs, 256, 0, stream>>>(cls_pred, sc_all, cls_all, hist);
    k_hsum<<<NBINS / 1024, 1024, 0, stream>>>(hist, merged, blksum);
    k_boundary<<<1, 1024, 0, stream>>>(merged, blksum, pB);
    k_compact<<<nbc, 256, 0, stream>>>(sc_all, pB, counter, cand);
    k_select<<<1, 1024, 0, stream>>>(cand, counter, sc_all, cls_all, reg_pred,
                                     anchors, out, sel_sc, sel_cls, vwords);
    k_supmat<<<(KTOP * 16) / 4, 256, 0, stream>>>(out, sel_cls, sup);
    k_nms<<<1, 64, 0, stream>>>(sup, vwords, sel_sc, out);
}